// Round 2
// baseline (250.110 us; speedup 1.0000x reference)
//
#include <hip/hip_runtime.h>
#include <hip/hip_bf16.h>

#define S_LEN 2048
#define NH 16
#define DK 64
#define DM 1024  // NH*DK
#define QBLK 64
#define KVBLK 64
#define NQT 32   // S_LEN/QBLK
#define KPAD 72  // padded row length (elements) -> 144B rows

typedef float f32x4 __attribute__((ext_vector_type(4)));
typedef __bf16 bf16x8 __attribute__((ext_vector_type(8)));
typedef __bf16 bf16x4 __attribute__((ext_vector_type(4)));

// One KV-tile worth of flash-attention update for one 64-row q-tile
// (this wave's 16 rows). All loops fully unrolled; arrays passed by
// reference stay in registers after inlining.
__device__ __forceinline__ void process_tile(
    const bf16x8 (&aq)[2], const __bf16* __restrict__ Kl,
    const __bf16* __restrict__ Vt, __bf16* __restrict__ Pslab,
    f32x4 (&o_acc)[4], float (&m_run)[4], float (&l_run)[4],
    int kv0, int q0, int w, int l16, int hi, bool diag) {
  // ---- S = Q K^T : lane holds S[hi*4+r][n*16+l16] ----
  f32x4 s[4];
#pragma unroll
  for (int n = 0; n < 4; ++n) s[n] = (f32x4){0.f, 0.f, 0.f, 0.f};
#pragma unroll
  for (int n = 0; n < 4; ++n)
#pragma unroll
    for (int c = 0; c < 2; ++c) {
      bf16x8 kf = *reinterpret_cast<const bf16x8*>(&Kl[(n * 16 + l16) * KPAD + c * 32 + hi * 8]);
      s[n] = __builtin_amdgcn_mfma_f32_16x16x32_bf16(aq[c], kf, s[n], 0, 0, 0);
    }

  // ---- scale + causal mask (diagonal tile only) ----
#pragma unroll
  for (int n = 0; n < 4; ++n) {
    const int jg = kv0 + n * 16 + l16;
#pragma unroll
    for (int r = 0; r < 4; ++r) {
      float sv = s[n][r] * 0.125f;
      if (diag) {
        int ig = q0 + w * 16 + hi * 4 + r;
        if (jg > ig) sv = -1e30f;
      }
      s[n][r] = sv;
    }
  }

  // ---- online softmax ----
  float rm[4], rs[4], al[4];
#pragma unroll
  for (int r = 0; r < 4; ++r)
    rm[r] = fmaxf(fmaxf(s[0][r], s[1][r]), fmaxf(s[2][r], s[3][r]));
#pragma unroll
  for (int msk = 1; msk < 16; msk <<= 1)
#pragma unroll
    for (int r = 0; r < 4; ++r)
      rm[r] = fmaxf(rm[r], __shfl_xor(rm[r], msk));
#pragma unroll
  for (int r = 0; r < 4; ++r) {
    float mn = fmaxf(m_run[r], rm[r]);
    al[r] = __expf(m_run[r] - mn);
    m_run[r] = mn;
    rs[r] = 0.f;
  }
#pragma unroll
  for (int n = 0; n < 4; ++n)
#pragma unroll
    for (int r = 0; r < 4; ++r) {
      float p = __expf(s[n][r] - m_run[r]);
      s[n][r] = p;
      rs[r] += p;
    }
#pragma unroll
  for (int msk = 1; msk < 16; msk <<= 1)
#pragma unroll
    for (int r = 0; r < 4; ++r)
      rs[r] += __shfl_xor(rs[r], msk);
#pragma unroll
  for (int r = 0; r < 4; ++r)
    l_run[r] = l_run[r] * al[r] + rs[r];
#pragma unroll
  for (int n = 0; n < 4; ++n)
#pragma unroll
    for (int r = 0; r < 4; ++r)
      o_acc[n][r] *= al[r];

  // ---- P -> LDS (wave-private slab; same-wave lgkmcnt orders write->read) ----
#pragma unroll
  for (int n = 0; n < 4; ++n)
#pragma unroll
    for (int r = 0; r < 4; ++r)
      Pslab[(hi * 4 + r) * KPAD + n * 16 + l16] = (__bf16)s[n][r];

  // ---- O += P V ----
  bf16x8 pf[2];
#pragma unroll
  for (int c = 0; c < 2; ++c)
    pf[c] = *reinterpret_cast<const bf16x8*>(&Pslab[l16 * KPAD + c * 32 + hi * 8]);
#pragma unroll
  for (int n = 0; n < 4; ++n)
#pragma unroll
    for (int c = 0; c < 2; ++c) {
      bf16x8 vf = *reinterpret_cast<const bf16x8*>(&Vt[(n * 16 + l16) * KPAD + c * 32 + hi * 8]);
      o_acc[n] = __builtin_amdgcn_mfma_f32_16x16x32_bf16(pf[c], vf, o_acc[n], 0, 0, 0);
    }
}

__device__ __forceinline__ void load_q_frags(const float* __restrict__ qp, int q0,
                                             int w, int l16, int hi, bf16x8 (&aq)[2]) {
  const float* qr = qp + (size_t)(q0 + w * 16 + l16) * DM;
#pragma unroll
  for (int c = 0; c < 2; ++c) {
    float4 f0 = *reinterpret_cast<const float4*>(qr + c * 32 + hi * 8);
    float4 f1 = *reinterpret_cast<const float4*>(qr + c * 32 + hi * 8 + 4);
    bf16x8 a;
    a[0] = (__bf16)f0.x; a[1] = (__bf16)f0.y; a[2] = (__bf16)f0.z; a[3] = (__bf16)f0.w;
    a[4] = (__bf16)f1.x; a[5] = (__bf16)f1.y; a[6] = (__bf16)f1.z; a[7] = (__bf16)f1.w;
    aq[c] = a;
  }
}

__device__ __forceinline__ void store_out(float* __restrict__ Og, int b, int h, int q0,
                                          int w, int l16, int hi,
                                          const f32x4 (&o_acc)[4], const float (&l_run)[4]) {
  float inv[4];
#pragma unroll
  for (int r = 0; r < 4; ++r) inv[r] = 1.0f / l_run[r];
  float* op = Og + ((size_t)(b * NH + h) * S_LEN + q0 + w * 16) * DK;
#pragma unroll
  for (int n = 0; n < 4; ++n)
#pragma unroll
    for (int r = 0; r < 4; ++r)
      op[(size_t)(hi * 4 + r) * DK + n * 16 + l16] = o_acc[n][r] * inv[r];
}

__global__ __launch_bounds__(256, 4)
void fa_fwd_causal(const float* __restrict__ Qg, const float* __restrict__ Kg,
                   const float* __restrict__ Vg, float* __restrict__ Og) {
  __shared__ __align__(16) __bf16 Kl[KVBLK * KPAD];   // [kv][d]
  __shared__ __align__(16) __bf16 Vt[DK * KPAD];      // [d][kv]  (transposed)
  __shared__ __align__(16) __bf16 Pl[QBLK * KPAD];    // wave-private 16-row slabs

  // 512 blocks: pair fastest (same head adjacent -> K/V L2 locality)
  const int bid  = blockIdx.x;
  const int pair = bid & 15;
  const int h    = (bid >> 4) & 15;
  const int b    = bid >> 8;

  // paired q-tiles: work = (qa+1)+(qb+1) = NQT+1 = 33 tiles, uniform
  const int qta = pair;           // 0..15
  const int qtb = NQT - 1 - pair; // 31..16
  const int q0a = qta * QBLK;
  const int q0b = qtb * QBLK;

  const int tid = threadIdx.x;
  const int w   = tid >> 6;
  const int l16 = tid & 15;
  const int hi  = (tid & 63) >> 4;

  const size_t base_in = (size_t)b * S_LEN * DM + (size_t)h * DK;
  const float* qp = Qg + base_in;
  const float* kp = Kg + base_in;
  const float* vp = Vg + base_in;

  bf16x8 aqA[2], aqB[2];
  load_q_frags(qp, q0a, w, l16, hi, aqA);
  load_q_frags(qp, q0b, w, l16, hi, aqB);

  f32x4 oA[4], oB[4];
  float mA[4], lA[4], mB[4], lB[4];
#pragma unroll
  for (int n = 0; n < 4; ++n) { oA[n] = (f32x4){0.f,0.f,0.f,0.f}; oB[n] = (f32x4){0.f,0.f,0.f,0.f}; }
#pragma unroll
  for (int r = 0; r < 4; ++r) { mA[r] = -1e30f; lA[r] = 0.f; mB[r] = -1e30f; lB[r] = 0.f; }

  __bf16* Pslab = &Pl[w * 16 * KPAD];

  const int n_tiles = qtb + 1;  // qtb >= qta
  for (int t = 0; t < n_tiles; ++t) {
    const int kv0 = t * KVBLK;
    __syncthreads();  // protect K/V LDS from previous iteration's readers
    // ---- stage K (row-major) and V (transposed) into LDS, f32 -> bf16 ----
#pragma unroll
    for (int it = 0; it < 4; ++it) {
      int f   = tid + it * 256;
      int row = f >> 4;
      int cb  = f & 15;
      const float4 k4 = *reinterpret_cast<const float4*>(kp + (size_t)(kv0 + row) * DM + cb * 4);
      const float4 v4 = *reinterpret_cast<const float4*>(vp + (size_t)(kv0 + row) * DM + cb * 4);
      bf16x4 kb;
      kb[0] = (__bf16)k4.x; kb[1] = (__bf16)k4.y; kb[2] = (__bf16)k4.z; kb[3] = (__bf16)k4.w;
      *reinterpret_cast<bf16x4*>(&Kl[row * KPAD + cb * 4]) = kb;
      Vt[(cb * 4 + 0) * KPAD + row] = (__bf16)v4.x;
      Vt[(cb * 4 + 1) * KPAD + row] = (__bf16)v4.y;
      Vt[(cb * 4 + 2) * KPAD + row] = (__bf16)v4.z;
      Vt[(cb * 4 + 3) * KPAD + row] = (__bf16)v4.w;
    }
    __syncthreads();

    // q-tile B always active (t <= qtb by loop bound)
    process_tile(aqB, Kl, Vt, Pslab, oB, mB, lB, kv0, q0b, w, l16, hi, t == qtb);
    // q-tile A active while t <= qta
    if (t <= qta)
      process_tile(aqA, Kl, Vt, Pslab, oA, mA, lA, kv0, q0a, w, l16, hi, t == qta);
  }

  store_out(Og, b, h, q0a, w, l16, hi, oA, lA);
  store_out(Og, b, h, q0b, w, l16, hi, oB, lB);
}

extern "C" void kernel_launch(void* const* d_in, const int* in_sizes, int n_in,
                              void* d_out, int out_size, void* d_ws, size_t ws_size,
                              hipStream_t stream) {
  const float* q = (const float*)d_in[0];
  const float* k = (const float*)d_in[1];
  const float* v = (const float*)d_in[2];
  // d_in[3] (mask) is deterministically causal-triu; implemented analytically.
  float* out = (float*)d_out;
  const int blocks = 2 * NH * (NQT / 2);  // 512 uniform-work blocks
  hipLaunchKernelGGL(fa_fwd_causal, dim3(blocks), dim3(256), 0, stream, q, k, v, out);
}

// Round 3
// 80.276 us; speedup vs baseline: 3.1156x; 3.1156x over previous
//
#include <hip/hip_runtime.h>
#include <hip/hip_bf16.h>

#define S_LEN 2048
#define NH 16
#define DK 64
#define DM 1024  // NH*DK
#define QBLK 64
#define KVBLK 64
#define NQT 32   // S_LEN/QBLK
#define KPAD 72  // padded row length (elements) -> 144B rows (b128 reads land at bank floor)

typedef float f32x4 __attribute__((ext_vector_type(4)));
typedef __bf16 bf16x8 __attribute__((ext_vector_type(8)));
typedef __bf16 bf16x4 __attribute__((ext_vector_type(4)));

// ---- prefetch: issue global loads for one KV tile into registers ----
__device__ __forceinline__ void kv_issue(const float* __restrict__ kp,
                                         const float* __restrict__ vp, int kv0,
                                         int tid, int w, int l,
                                         float4 (&kr)[4], float (&vr)[16]) {
#pragma unroll
  for (int it = 0; it < 4; ++it) {
    int f = tid + it * 256;
    int row = f >> 4, cb = f & 15;
    kr[it] = *reinterpret_cast<const float4*>(kp + (size_t)(kv0 + row) * DM + cb * 4);
  }
  // V read transposed: lane = d (coalesced 256B rows), 4 kv per unit
#pragma unroll
  for (int it = 0; it < 4; ++it) {
    int kvq = w + it * 4;
#pragma unroll
    for (int j = 0; j < 4; ++j)
      vr[it * 4 + j] = vp[(size_t)(kv0 + kvq * 4 + j) * DM + l];
  }
}

// ---- convert + write prefetched registers into LDS buffers ----
__device__ __forceinline__ void kv_write(__bf16* __restrict__ Kb, __bf16* __restrict__ Vb,
                                         int tid, int w, int l, int vxor,
                                         const float4 (&kr)[4], const float (&vr)[16]) {
#pragma unroll
  for (int it = 0; it < 4; ++it) {
    int f = tid + it * 256;
    int row = f >> 4, cb = f & 15;
    bf16x4 kb;
    kb[0] = (__bf16)kr[it].x; kb[1] = (__bf16)kr[it].y;
    kb[2] = (__bf16)kr[it].z; kb[3] = (__bf16)kr[it].w;
    *reinterpret_cast<bf16x4*>(&Kb[row * KPAD + cb * 4]) = kb;
  }
#pragma unroll
  for (int it = 0; it < 4; ++it) {
    int kvq = w + it * 4;
    bf16x4 vb;
#pragma unroll
    for (int j = 0; j < 4; ++j) vb[j] = (__bf16)vr[it * 4 + j];
    // Vt[d][kv], row d = lane; 16B-granular XOR on kv units breaks the
    // 8-lane stride-144B bank collision (write ~floor, read unswizzles)
    char* p = reinterpret_cast<char*>(Vb) + (((l * KPAD + kvq * 4) * 2) ^ vxor);
    *reinterpret_cast<bf16x4*>(p) = vb;
  }
}

// ---- one KV-tile flash update for one q-tile (this wave's 16 rows) ----
__device__ __forceinline__ void process_tile(
    const bf16x8 (&aq)[2], const __bf16* __restrict__ Kl,
    const __bf16* __restrict__ Vt, __bf16* __restrict__ Pslab,
    f32x4 (&o_acc)[4], float (&m_run)[4], float (&l_run)[4],
    int kv0, int q0, int w, int l16, int hi, int rxor, bool diag) {
  f32x4 s[4];
#pragma unroll
  for (int n = 0; n < 4; ++n) s[n] = (f32x4){0.f, 0.f, 0.f, 0.f};
#pragma unroll
  for (int n = 0; n < 4; ++n)
#pragma unroll
    for (int c = 0; c < 2; ++c) {
      bf16x8 kf = *reinterpret_cast<const bf16x8*>(&Kl[(n * 16 + l16) * KPAD + c * 32 + hi * 8]);
      s[n] = __builtin_amdgcn_mfma_f32_16x16x32_bf16(aq[c], kf, s[n], 0, 0, 0);
    }

#pragma unroll
  for (int n = 0; n < 4; ++n) {
    const int jg = kv0 + n * 16 + l16;
#pragma unroll
    for (int r = 0; r < 4; ++r) {
      float sv = s[n][r] * 0.125f;
      if (diag) {
        int ig = q0 + w * 16 + hi * 4 + r;
        if (jg > ig) sv = -1e30f;
      }
      s[n][r] = sv;
    }
  }

  float rm[4], rs[4], al[4];
#pragma unroll
  for (int r = 0; r < 4; ++r)
    rm[r] = fmaxf(fmaxf(s[0][r], s[1][r]), fmaxf(s[2][r], s[3][r]));
#pragma unroll
  for (int msk = 1; msk < 16; msk <<= 1)
#pragma unroll
    for (int r = 0; r < 4; ++r)
      rm[r] = fmaxf(rm[r], __shfl_xor(rm[r], msk));
#pragma unroll
  for (int r = 0; r < 4; ++r) {
    float mn = fmaxf(m_run[r], rm[r]);
    al[r] = __expf(m_run[r] - mn);
    m_run[r] = mn;
    rs[r] = 0.f;
  }
#pragma unroll
  for (int n = 0; n < 4; ++n)
#pragma unroll
    for (int r = 0; r < 4; ++r) {
      float p = __expf(s[n][r] - m_run[r]);
      s[n][r] = p;
      rs[r] += p;
    }
#pragma unroll
  for (int msk = 1; msk < 16; msk <<= 1)
#pragma unroll
    for (int r = 0; r < 4; ++r)
      rs[r] += __shfl_xor(rs[r], msk);
#pragma unroll
  for (int r = 0; r < 4; ++r)
    l_run[r] = l_run[r] * al[r] + rs[r];
#pragma unroll
  for (int n = 0; n < 4; ++n)
#pragma unroll
    for (int r = 0; r < 4; ++r)
      o_acc[n][r] *= al[r];

  // P -> wave-private LDS slab (same-wave lgkmcnt orders write->read)
#pragma unroll
  for (int n = 0; n < 4; ++n)
#pragma unroll
    for (int r = 0; r < 4; ++r)
      Pslab[(hi * 4 + r) * KPAD + n * 16 + l16] = (__bf16)s[n][r];

  bf16x8 pf[2];
#pragma unroll
  for (int c = 0; c < 2; ++c)
    pf[c] = *reinterpret_cast<const bf16x8*>(&Pslab[l16 * KPAD + c * 32 + hi * 8]);
#pragma unroll
  for (int n = 0; n < 4; ++n)
#pragma unroll
    for (int c = 0; c < 2; ++c) {
      const char* vpb = reinterpret_cast<const char*>(Vt) +
                        ((((n * 16 + l16) * KPAD + c * 32 + hi * 8) * 2) ^ rxor);
      bf16x8 vf = *reinterpret_cast<const bf16x8*>(vpb);
      o_acc[n] = __builtin_amdgcn_mfma_f32_16x16x32_bf16(pf[c], vf, o_acc[n], 0, 0, 0);
    }
}

__device__ __forceinline__ void load_q_frags(const float* __restrict__ qp, int q0,
                                             int w, int l16, int hi, bf16x8 (&aq)[2]) {
  const float* qr = qp + (size_t)(q0 + w * 16 + l16) * DM;
#pragma unroll
  for (int c = 0; c < 2; ++c) {
    float4 f0 = *reinterpret_cast<const float4*>(qr + c * 32 + hi * 8);
    float4 f1 = *reinterpret_cast<const float4*>(qr + c * 32 + hi * 8 + 4);
    bf16x8 a;
    a[0] = (__bf16)f0.x; a[1] = (__bf16)f0.y; a[2] = (__bf16)f0.z; a[3] = (__bf16)f0.w;
    a[4] = (__bf16)f1.x; a[5] = (__bf16)f1.y; a[6] = (__bf16)f1.z; a[7] = (__bf16)f1.w;
    aq[c] = a;
  }
}

__device__ __forceinline__ void store_out(float* __restrict__ Og, int b, int h, int q0,
                                          int w, int l16, int hi,
                                          const f32x4 (&o_acc)[4], const float (&l_run)[4]) {
  float inv[4];
#pragma unroll
  for (int r = 0; r < 4; ++r) inv[r] = 1.0f / l_run[r];
  float* op = Og + ((size_t)(b * NH + h) * S_LEN + q0 + w * 16) * DK;
#pragma unroll
  for (int n = 0; n < 4; ++n)
#pragma unroll
    for (int r = 0; r < 4; ++r)
      op[(size_t)(hi * 4 + r) * DK + n * 16 + l16] = o_acc[n][r] * inv[r];
}

__global__ __launch_bounds__(256, 2)  // 256-VGPR budget: NO spills (round-2 lesson)
void fa_fwd_causal(const float* __restrict__ Qg, const float* __restrict__ Kg,
                   const float* __restrict__ Vg, float* __restrict__ Og) {
  __shared__ __align__(16) __bf16 Kl[2][KVBLK * KPAD];  // double-buffered
  __shared__ __align__(16) __bf16 Vt[2][DK * KPAD];     // transposed, double-buffered
  __shared__ __align__(16) __bf16 Pl[QBLK * KPAD];      // wave-private slabs

  // XCD-pinned decode (dispatch round-robins bid%8 across XCDs): all 16
  // blocks of one head land on one XCD -> its K+V (1MB f32) L2-resident.
  const int bid  = blockIdx.x;
  const int xcd  = bid & 7;
  const int s    = bid >> 3;
  const int pair = s & 15;
  const int b    = (s >> 4) & 1;
  const int h    = xcd + 8 * ((s >> 5) & 1);

  // paired q-tiles: compute = (qta+1)+(qtb+1) = 33 tiles/block, uniform
  const int qta = pair;
  const int qtb = NQT - 1 - pair;
  const int q0a = qta * QBLK;
  const int q0b = qtb * QBLK;

  const int tid = threadIdx.x;
  const int w   = tid >> 6;
  const int l   = tid & 63;
  const int l16 = l & 15;
  const int hi  = l >> 4;
  const int vxor = ((l >> 3) & 1) << 4;    // V write-side swizzle (row = d = lane)
  const int rxor = ((l16 >> 3) & 1) << 4;  // V read-side swizzle (row = n*16+l16)

  const size_t base_in = (size_t)b * S_LEN * DM + (size_t)h * DK;
  const float* qp = Qg + base_in;
  const float* kp = Kg + base_in;
  const float* vp = Vg + base_in;

  bf16x8 aqA[2], aqB[2];
  load_q_frags(qp, q0a, w, l16, hi, aqA);
  load_q_frags(qp, q0b, w, l16, hi, aqB);

  f32x4 oA[4], oB[4];
  float mA[4], lA[4], mB[4], lB[4];
#pragma unroll
  for (int n = 0; n < 4; ++n) { oA[n] = (f32x4){0.f,0.f,0.f,0.f}; oB[n] = (f32x4){0.f,0.f,0.f,0.f}; }
#pragma unroll
  for (int r = 0; r < 4; ++r) { mA[r] = -1e30f; lA[r] = 0.f; mB[r] = -1e30f; lB[r] = 0.f; }

  __bf16* Pslab = &Pl[w * 16 * KPAD];

  // Pipeline: issue loads(t+1) before barrier; compute(t) hides HBM latency.
  float4 kr[4];
  float  vr[16];
  kv_issue(kp, vp, 0, tid, w, l, kr, vr);

  int cur = 0;
  const int n_tiles = qtb + 1;
  for (int t = 0; t < n_tiles; ++t) {
    // write tile t (regs->LDS); safe: all waves finished compute(t-2) on this
    // buffer before passing barrier(t-1), which precedes this write.
    kv_write(Kl[cur], Vt[cur], tid, w, l, vxor, kr, vr);
    if (t + 1 < n_tiles) kv_issue(kp, vp, (t + 1) * KVBLK, tid, w, l, kr, vr);
    __syncthreads();  // one barrier per tile
    process_tile(aqB, Kl[cur], Vt[cur], Pslab, oB, mB, lB, t * KVBLK, q0b, w, l16, hi, rxor, t == qtb);
    if (t <= qta)
      process_tile(aqA, Kl[cur], Vt[cur], Pslab, oA, mA, lA, t * KVBLK, q0a, w, l16, hi, rxor, t == qta);
    cur ^= 1;
  }

  store_out(Og, b, h, q0a, w, l16, hi, oA, lA);
  store_out(Og, b, h, q0b, w, l16, hi, oB, lB);
}

extern "C" void kernel_launch(void* const* d_in, const int* in_sizes, int n_in,
                              void* d_out, int out_size, void* d_ws, size_t ws_size,
                              hipStream_t stream) {
  const float* q = (const float*)d_in[0];
  const float* k = (const float*)d_in[1];
  const float* v = (const float*)d_in[2];
  // d_in[3] (mask) is deterministically causal-triu; implemented analytically.
  float* out = (float*)d_out;
  const int blocks = 2 * NH * (NQT / 2);  // 512 uniform-work blocks
  hipLaunchKernelGGL(fa_fwd_causal, dim3(blocks), dim3(256), 0, stream, q, k, v, out);
}